// Round 9
// baseline (336.999 us; speedup 1.0000x reference)
//
#include <hip/hip_runtime.h>

#define B_  1024
#define T_  128
#define V_  89
#define H_  256
#define NB2 256          // fused-kernel blocks
#define PT_ 4            // timesteps per phase
#define NPH 32           // phases

typedef __attribute__((ext_vector_type(8))) short bf16x8;
typedef __attribute__((ext_vector_type(4))) float f32x4;
typedef __attribute__((ext_vector_type(4))) unsigned short u16x4;

__device__ __forceinline__ short f2bs(float f){
    unsigned u = __float_as_uint(f);
    unsigned r = (u + 0x7FFFu + ((u>>16)&1u)) >> 16;
    return (short)r;
}
__device__ __forceinline__ float s2f(unsigned short s){
    return __uint_as_float(((unsigned)s) << 16);
}
__device__ __forceinline__ float sig_(float x){ return 1.f/(1.f+__expf(-x)); }
__device__ __forceinline__ float tanh_(float x){ return 2.f/(1.f+__expf(-2.f*x)) - 1.f; }

// ---------------------------------------------------------------- W_hh fp32 -> fp8 [768][256]
__global__ __launch_bounds__(256) void k_cvt_fp8(
    const float* __restrict__ src, unsigned char* __restrict__ dst, int n)
{
    int i = blockIdx.x*256 + threadIdx.x;
    if (i*4 >= n) return;
    float f0 = src[i*4+0], f1 = src[i*4+1], f2 = src[i*4+2], f3 = src[i*4+3];
    int w = __builtin_amdgcn_cvt_pk_fp8_f32(f0, f1, 0, false);
    w     = __builtin_amdgcn_cvt_pk_fp8_f32(f2, f3, w, true);
    ((int*)dst)[i] = w;
}

// ---------------------------------------------------------------- W_ih+b_ih -> fp8 [768][192]
// rows k: 0..177 = W_ih cols, 178 = bias, 179..191 = 0
__global__ __launch_bounds__(256) void k_prep_wih8(
    const float* __restrict__ W_ih, const float* __restrict__ b_ih,
    unsigned char* __restrict__ dst)
{
    int i = blockIdx.x*256 + threadIdx.x;      // dword index over 768*48
    if (i >= 768*48) return;
    int n = i / 48, k4 = (i - n*48)*4;
    float f[4];
    #pragma unroll
    for (int j = 0; j < 4; ++j) {
        int k = k4 + j;
        f[j] = (k < 178) ? W_ih[(size_t)n*178 + k] : (k == 178 ? b_ih[n] : 0.f);
    }
    int w = __builtin_amdgcn_cvt_pk_fp8_f32(f[0], f[1], 0, false);
    w     = __builtin_amdgcn_cvt_pk_fp8_f32(f[2], f[3], w, true);
    ((int*)dst)[i] = w;
}

// ---------------------------------------------------------------- W_h+b_h -> bf16 [256][96]
__global__ __launch_bounds__(256) void k_prep_whp(
    const float* __restrict__ W_h, const float* __restrict__ b_h,
    short* __restrict__ dst)
{
    int i = blockIdx.x*256 + threadIdx.x;
    if (i >= 256*96) return;
    int n = i / 96, k = i - n*96;
    float v = (k < V_) ? W_h[(size_t)n*V_ + k] : (k == V_ ? b_h[n] : 0.f);
    dst[i] = f2bs(v);
}

// ---------------------------------------------------------------- gamma_h producer
// grid (256, 32): x = 4-batch group, y = phase (4 t). Output fragment-native:
// gdv u16x4 idx = (p*1024 + bx*4 + g8)*256 + col ; v[rr] = gamma(b, t=p*4+rr, col)
__global__ __launch_bounds__(256) void k_gammah(
    const float* __restrict__ deltas, const short* __restrict__ whp,
    unsigned short* __restrict__ gdv)
{
    __shared__ short dl2[16*104] __attribute__((aligned(16)));
    int tid = threadIdx.x;
    int bx = blockIdx.x, p = blockIdx.y;
    for (int i = tid; i < 16*96; i += 256) {
        int m = i / 96, k = i - m*96;
        int b = bx*4 + (m>>2), t = p*4 + (m&3);
        float val = 0.f;
        if (k < V_)       val = deltas[((size_t)b*T_ + t)*V_ + k];
        else if (k == V_) val = 1.0f;
        dl2[m*104 + k] = f2bs(val);
    }
    __syncthreads();
    int lane = tid & 63, wv = tid >> 6;
    int l15 = lane & 15, g8 = lane >> 4;
    f32x4 z4 = {0.f,0.f,0.f,0.f};
    f32x4 acc[4];
    #pragma unroll
    for (int nt = 0; nt < 4; ++nt) acc[nt] = z4;
    #pragma unroll
    for (int kt = 0; kt < 3; ++kt) {
        bf16x8 a = *(const bf16x8*)&dl2[l15*104 + kt*32 + g8*8];
        #pragma unroll
        for (int nt = 0; nt < 4; ++nt) {
            int cg = wv*64 + nt*16 + l15;
            bf16x8 bb = *(const bf16x8*)(whp + (size_t)cg*96 + kt*32 + g8*8);
            acc[nt] = __builtin_amdgcn_mfma_f32_16x16x32_bf16(a, bb, acc[nt], 0,0,0);
        }
    }
    #pragma unroll
    for (int nt = 0; nt < 4; ++nt) {
        int cg = wv*64 + nt*16 + l15;
        u16x4 v;
        #pragma unroll
        for (int rr = 0; rr < 4; ++rr)
            v[rr] = (unsigned short)f2bs(__expf(-fmaxf(acc[nt][rr], 0.f)));
        ((u16x4*)gdv)[((size_t)(p*1024 + bx*4 + g8))*256 + cg] = v;
    }
}

// ---------------------------------------------------------------- fused kernel
// 256 blocks x 1024 thr, FORCED 4 waves/EU (1 block/CU) => 128-VGPR budget so
// W_ih fp8 (36 VGPR) + W_hh fp8 (48 VGPR) stay register-resident.
__global__ __launch_bounds__(1024)
__attribute__((amdgpu_waves_per_eu(4, 4)))
void k_fused(
    const float* __restrict__ x, const float* __restrict__ mask,
    const float* __restrict__ deltas, const float* __restrict__ meanset,
    const float* __restrict__ W_x, const float* __restrict__ b_x,
    const unsigned char* __restrict__ wihb8, const unsigned char* __restrict__ whh8,
    const unsigned short* __restrict__ gdv, const float* __restrict__ b_hh,
    const float* __restrict__ W_cls, const float* __restrict__ b_cls,
    float* __restrict__ ximp, float* __restrict__ numpart, float* __restrict__ denpart,
    float* __restrict__ yout, float* __restrict__ yscore)
{
    __shared__ unsigned char xl[16*200] __attribute__((aligned(16)));  // fp8 [x_h|m|1|0]
    __shared__ unsigned char hlds[2][4*272] __attribute__((aligned(16)));
    __shared__ float lossn[PT_][360], lossd[PT_][360];
    __shared__ float yred[4][16];

    int tid = threadIdx.x;
    int lane = tid & 63, wv = tid >> 6;
    int l15 = lane & 15, g8 = lane >> 4;
    int blk = blockIdx.x;
    int c = wv*16 + l15;

    // static pads of xl: col 178 = fp8(1.0)=0x38, 179..191 = 0
    for (int i = tid; i < 16*14; i += 1024) {
        int r = i / 14, k = 178 + (i - r*14);
        xl[r*200 + k] = (k == 178) ? 0x38 : 0;
    }

    // owners: one per (row, v)
    bool own = (tid < 4*V_);
    int r_o = tid / V_, v_o = tid - r_o*V_;
    int b_o = blk*4 + r_o;
    float wxd = 0.f, bx = 0.f, mnv = 0.f, last = 0.f;
    if (own) { wxd = W_x[v_o*V_ + v_o]; bx = b_x[v_o]; mnv = meanset[v_o]; }

    // register-resident weights
    long wih[3][6];
    #pragma unroll
    for (int g = 0; g < 3; ++g)
        #pragma unroll
        for (int kt = 0; kt < 6; ++kt)
            wih[g][kt] = *(const long*)(wihb8 + (size_t)(g*H_ + c)*192 + kt*32 + g8*8);
    long wf[3][8];
    #pragma unroll
    for (int g = 0; g < 3; ++g)
        #pragma unroll
        for (int kt = 0; kt < 8; ++kt)
            wf[g][kt] = *(const long*)(whh8 + (size_t)(g*H_ + c)*H_ + kt*32 + g8*8);
    float bhh0 = b_hh[c], bhh1 = b_hh[H_ + c], bhh2 = b_hh[2*H_ + c];

    float h = 0.f;

    for (int p = 0; p < NPH; ++p) {
        // ---- gamma prefetch (fragment-native, coalesced 8B/lane)
        u16x4 gdl = ((const u16x4*)gdv)[((size_t)(p*1024 + blk*4 + g8))*256 + c];

        // ================= stage: impute + ffill + loss + xl tile
        if (own) {
            const float* xb = x      + ((size_t)b_o*T_ + p*PT_)*V_ + v_o;
            const float* mb = mask   + ((size_t)b_o*T_ + p*PT_)*V_ + v_o;
            const float* db = deltas + ((size_t)b_o*T_ + p*PT_)*V_ + v_o;
            float xv[PT_], mv[PT_], dv[PT_];
            #pragma unroll
            for (int lt = 0; lt < PT_; ++lt) {
                xv[lt] = xb[lt*V_]; mv[lt] = mb[lt*V_]; dv[lt] = db[lt*V_];
            }
            #pragma unroll
            for (int lt = 0; lt < PT_; ++lt) {
                float xt = xv[lt], m = mv[lt], d = dv[lt];
                float gx = __expf(-fmaxf(fmaf(d, wxd, bx), 0.f));
                last = (m > 0.f) ? xt : last;
                float xu = gx*last + (1.f-gx)*mnv;
                float xh = m*xt + (1.f-m)*xu;
                ximp[((size_t)b_o*T_ + p*PT_ + lt)*V_ + v_o] = xh;
                int mr = r_o*4 + lt;
                int pk = __builtin_amdgcn_cvt_pk_fp8_f32(xh, m, 0, false);
                xl[mr*200 + v_o]      = (unsigned char)(pk & 0xFF);
                xl[mr*200 + V_ + v_o] = (unsigned char)((pk >> 8) & 0xFF);
                lossn[lt][tid] = fabsf(xt - xu)*m;
                lossd[lt][tid] = m;
            }
        }
        __syncthreads();

        // ---- loss reduce (wave 0)
        if (tid < 64) {
            int lt = tid >> 4, part = tid & 15;
            float n = 0.f, ds = 0.f;
            for (int j = part; j < 4*V_; j += 16) { n += lossn[lt][j]; ds += lossd[lt][j]; }
            n += __shfl_xor(n, 1); ds += __shfl_xor(ds, 1);
            n += __shfl_xor(n, 2); ds += __shfl_xor(ds, 2);
            n += __shfl_xor(n, 4); ds += __shfl_xor(ds, 4);
            n += __shfl_xor(n, 8); ds += __shfl_xor(ds, 8);
            if (part == 0) {
                int t = p*PT_ + lt;
                numpart[t*NB2 + blk] = n;
                denpart[t*NB2 + blk] = ds;
            }
        }

        // ================= gates GEMM: fp8, K=192, bias folded (init 0)
        f32x4 ar = {0.f,0.f,0.f,0.f};
        f32x4 az = {0.f,0.f,0.f,0.f};
        f32x4 an = {0.f,0.f,0.f,0.f};
        #pragma unroll
        for (int kt = 0; kt < 6; ++kt) {
            long a = *(const long*)&xl[l15*200 + kt*32 + g8*8];
            ar = __builtin_amdgcn_mfma_f32_16x16x32_fp8_fp8(a, wih[0][kt], ar, 0,0,0);
            az = __builtin_amdgcn_mfma_f32_16x16x32_fp8_fp8(a, wih[1][kt], az, 0,0,0);
            an = __builtin_amdgcn_mfma_f32_16x16x32_fp8_fp8(a, wih[2][kt], an, 0,0,0);
        }

        // ================= recurrence: 4 steps
        #pragma unroll
        for (int lt = 0; lt < PT_; ++lt) {
            const int cb = lt & 1;
            float hd = h * s2f(gdl[lt]);
            int pk = __builtin_amdgcn_cvt_pk_fp8_f32(hd, hd, 0, false);
            hlds[cb][g8*272 + c] = (unsigned char)(pk & 0xFF);
            __syncthreads();
            f32x4 s0 = {bhh0,bhh0,bhh0,bhh0};
            f32x4 s1 = {bhh1,bhh1,bhh1,bhh1};
            f32x4 s2 = {bhh2,bhh2,bhh2,bhh2};
            #pragma unroll
            for (int kt = 0; kt < 8; ++kt) {
                long a = *(const long*)&hlds[cb][(l15>>2)*272 + kt*32 + g8*8];
                s0 = __builtin_amdgcn_mfma_f32_16x16x32_fp8_fp8(a, wf[0][kt], s0, 0,0,0);
                s1 = __builtin_amdgcn_mfma_f32_16x16x32_fp8_fp8(a, wf[1][kt], s1, 0,0,0);
                s2 = __builtin_amdgcn_mfma_f32_16x16x32_fp8_fp8(a, wf[2][kt], s2, 0,0,0);
            }
            float rg = sig_(ar[lt] + s0[0]);
            float zg = sig_(az[lt] + s1[0]);
            float ng = tanh_(an[lt] + rg*s2[0]);
            h = (1.f - zg)*ng + zg*hd;
        }
    }

    // ================= epilogue
    {
        float pr = h * W_cls[c];
        pr += __shfl_xor(pr, 1);
        pr += __shfl_xor(pr, 2);
        pr += __shfl_xor(pr, 4);
        pr += __shfl_xor(pr, 8);
        if (l15 == 0) yred[g8][wv] = pr;
        __syncthreads();
        if (tid < 4) {
            float s = b_cls[0];
            #pragma unroll
            for (int ww = 0; ww < 16; ++ww) s += yred[tid][ww];
            yout[blk*4 + tid]   = s;
            yscore[blk*4 + tid] = 1.f/(1.f+__expf(-s));
        }
    }
}

// ---------------------------------------------------------------- loss stage 1
__global__ __launch_bounds__(256) void k_loss_t(
    const float* __restrict__ numpart, const float* __restrict__ denpart,
    float* __restrict__ tpart)
{
    int t = blockIdx.x, tid = threadIdx.x;
    float n = numpart[t*NB2 + tid];
    float d = denpart[t*NB2 + tid];
    for (int off = 32; off; off >>= 1) { n += __shfl_down(n, off); d += __shfl_down(d, off); }
    __shared__ float sn[4], sd[4];
    int lane = tid & 63, wid = tid >> 6;
    if (lane == 0) { sn[wid] = n; sd[wid] = d; }
    __syncthreads();
    if (tid == 0) {
        float nn = sn[0]+sn[1]+sn[2]+sn[3], dd = sd[0]+sd[1]+sd[2]+sd[3];
        tpart[t] = nn / (dd + 1e-5f);
    }
}

// ---------------------------------------------------------------- loss stage 2
__global__ __launch_bounds__(128) void k_loss_final(
    const float* __restrict__ tpart, float* __restrict__ out_loss)
{
    int tid = threadIdx.x;
    float s = tpart[tid];
    for (int off = 32; off; off >>= 1) s += __shfl_down(s, off);
    __shared__ float sp[2];
    if ((tid&63)==0) sp[tid>>6] = s;
    __syncthreads();
    if (tid==0) out_loss[0] = sp[0] + sp[1];
}

static inline size_t al256(size_t x){ return (x + 255) & ~(size_t)255; }

extern "C" void kernel_launch(void* const* d_in, const int* in_sizes, int n_in,
                              void* d_out, int out_size, void* d_ws, size_t ws_size,
                              hipStream_t stream)
{
    const float* x      = (const float*)d_in[0];
    const float* mask   = (const float*)d_in[1];
    const float* deltas = (const float*)d_in[2];
    const float* meanset= (const float*)d_in[3];
    const float* W_h    = (const float*)d_in[4];
    const float* b_h    = (const float*)d_in[5];
    const float* W_x    = (const float*)d_in[6];
    const float* b_x    = (const float*)d_in[7];
    const float* W_ih   = (const float*)d_in[8];
    const float* b_ih   = (const float*)d_in[9];
    const float* W_hh   = (const float*)d_in[10];
    const float* b_hh   = (const float*)d_in[11];
    const float* W_cls  = (const float*)d_in[12];
    const float* b_cls  = (const float*)d_in[13];

    float* out    = (float*)d_out;
    float* ximp   = out;                        // B*T*V
    float* xloss  = out + (size_t)B_*T_*V_;     // 1
    float* yout   = xloss + 1;                  // B
    float* yscore = yout + B_;                  // B

    size_t off = 0;
    size_t off_whh8 = off; off = al256(off + (size_t)768*256);      // fp8
    size_t off_wih8 = off; off = al256(off + (size_t)768*192);      // fp8, bias folded
    size_t off_whp  = off; off = al256(off + (size_t)256*96*2);     // bf16, bias folded
    size_t off_gdv  = off; off = al256(off + (size_t)B_*T_*H_*2);   // gamma bf16 frag-native
    size_t off_np   = off; off = al256(off + (size_t)T_*NB2*4);
    size_t off_dp   = off; off = al256(off + (size_t)T_*NB2*4);
    size_t off_tp   = off; off = al256(off + (size_t)T_*4);
    if (off > ws_size) return;

    char* ws = (char*)d_ws;
    unsigned char* whh8 = (unsigned char*)(ws + off_whh8);
    unsigned char* wih8 = (unsigned char*)(ws + off_wih8);
    short* whp    = (short*)(ws + off_whp);
    unsigned short* gdv = (unsigned short*)(ws + off_gdv);
    float* numpart= (float*)(ws + off_np);
    float* denpart= (float*)(ws + off_dp);
    float* tpart  = (float*)(ws + off_tp);

    hipLaunchKernelGGL(k_cvt_fp8, dim3((768*256/4+255)/256), dim3(256), 0, stream, W_hh, whh8, 768*256);
    hipLaunchKernelGGL(k_prep_wih8, dim3((768*48+255)/256), dim3(256), 0, stream, W_ih, b_ih, wih8);
    hipLaunchKernelGGL(k_prep_whp, dim3((256*96+255)/256), dim3(256), 0, stream, W_h, b_h, whp);
    hipLaunchKernelGGL(k_gammah, dim3(256, 32), dim3(256), 0, stream, deltas, whp, gdv);
    hipLaunchKernelGGL(k_fused, dim3(NB2), dim3(1024), 0, stream,
                       x, mask, deltas, meanset, W_x, b_x,
                       wih8, whh8, gdv, b_hh, W_cls, b_cls,
                       ximp, numpart, denpart, yout, yscore);
    hipLaunchKernelGGL(k_loss_t, dim3(T_), dim3(256), 0, stream, numpart, denpart, tpart);
    hipLaunchKernelGGL(k_loss_final, dim3(1), dim3(128), 0, stream, tpart, xloss);
}

// Round 10
// 315.285 us; speedup vs baseline: 1.0689x; 1.0689x over previous
//
#include <hip/hip_runtime.h>

#define B_  1024
#define T_  128
#define V_  89
#define H_  256
#define NB2 256          // fused-kernel blocks
#define PT_ 4            // timesteps per phase
#define NPH 32           // phases

typedef __attribute__((ext_vector_type(8))) short bf16x8;
typedef __attribute__((ext_vector_type(4))) float f32x4;
typedef __attribute__((ext_vector_type(4))) unsigned short u16x4;

__device__ __forceinline__ short f2bs(float f){
    unsigned u = __float_as_uint(f);
    unsigned r = (u + 0x7FFFu + ((u>>16)&1u)) >> 16;
    return (short)r;
}
__device__ __forceinline__ float s2f(unsigned short s){
    return __uint_as_float(((unsigned)s) << 16);
}
__device__ __forceinline__ float sig_(float x){ return 1.f/(1.f+__expf(-x)); }
__device__ __forceinline__ float tanh_(float x){ return 2.f/(1.f+__expf(-2.f*x)) - 1.f; }

// ---------------------------------------------------------------- W_hh fp32 -> fp8 [768][256]
__global__ __launch_bounds__(256) void k_cvt_fp8(
    const float* __restrict__ src, unsigned char* __restrict__ dst, int n)
{
    int i = blockIdx.x*256 + threadIdx.x;
    if (i*4 >= n) return;
    float f0 = src[i*4+0], f1 = src[i*4+1], f2 = src[i*4+2], f3 = src[i*4+3];
    int w = __builtin_amdgcn_cvt_pk_fp8_f32(f0, f1, 0, false);
    w     = __builtin_amdgcn_cvt_pk_fp8_f32(f2, f3, w, true);
    ((int*)dst)[i] = w;
}

// ---------------------------------------------------------------- W_ih+b_ih -> fp8 [768][192]
__global__ __launch_bounds__(256) void k_prep_wih8(
    const float* __restrict__ W_ih, const float* __restrict__ b_ih,
    unsigned char* __restrict__ dst)
{
    int i = blockIdx.x*256 + threadIdx.x;      // dword index over 768*48
    if (i >= 768*48) return;
    int n = i / 48, k4 = (i - n*48)*4;
    float f[4];
    #pragma unroll
    for (int j = 0; j < 4; ++j) {
        int k = k4 + j;
        f[j] = (k < 178) ? W_ih[(size_t)n*178 + k] : (k == 178 ? b_ih[n] : 0.f);
    }
    int w = __builtin_amdgcn_cvt_pk_fp8_f32(f[0], f[1], 0, false);
    w     = __builtin_amdgcn_cvt_pk_fp8_f32(f[2], f[3], w, true);
    ((int*)dst)[i] = w;
}

// ---------------------------------------------------------------- W_h+b_h -> bf16 [256][96]
__global__ __launch_bounds__(256) void k_prep_whp(
    const float* __restrict__ W_h, const float* __restrict__ b_h,
    short* __restrict__ dst)
{
    int i = blockIdx.x*256 + threadIdx.x;
    if (i >= 256*96) return;
    int n = i / 96, k = i - n*96;
    float v = (k < V_) ? W_h[(size_t)n*V_ + k] : (k == V_ ? b_h[n] : 0.f);
    dst[i] = f2bs(v);
}

// ---------------------------------------------------------------- gamma_h producer
// gdv u16x4 idx = (p*1024 + bx*4 + g8)*256 + col ; v[rr] = gamma(b, t=p*4+rr, col)
__global__ __launch_bounds__(256) void k_gammah(
    const float* __restrict__ deltas, const short* __restrict__ whp,
    unsigned short* __restrict__ gdv)
{
    __shared__ short dl2[16*104] __attribute__((aligned(16)));
    int tid = threadIdx.x;
    int bx = blockIdx.x, p = blockIdx.y;
    for (int i = tid; i < 16*96; i += 256) {
        int m = i / 96, k = i - m*96;
        int b = bx*4 + (m>>2), t = p*4 + (m&3);
        float val = 0.f;
        if (k < V_)       val = deltas[((size_t)b*T_ + t)*V_ + k];
        else if (k == V_) val = 1.0f;
        dl2[m*104 + k] = f2bs(val);
    }
    __syncthreads();
    int lane = tid & 63, wv = tid >> 6;
    int l15 = lane & 15, g8 = lane >> 4;
    f32x4 z4 = {0.f,0.f,0.f,0.f};
    f32x4 acc[4];
    #pragma unroll
    for (int nt = 0; nt < 4; ++nt) acc[nt] = z4;
    #pragma unroll
    for (int kt = 0; kt < 3; ++kt) {
        bf16x8 a = *(const bf16x8*)&dl2[l15*104 + kt*32 + g8*8];
        #pragma unroll
        for (int nt = 0; nt < 4; ++nt) {
            int cg = wv*64 + nt*16 + l15;
            bf16x8 bb = *(const bf16x8*)(whp + (size_t)cg*96 + kt*32 + g8*8);
            acc[nt] = __builtin_amdgcn_mfma_f32_16x16x32_bf16(a, bb, acc[nt], 0,0,0);
        }
    }
    #pragma unroll
    for (int nt = 0; nt < 4; ++nt) {
        int cg = wv*64 + nt*16 + l15;
        u16x4 v;
        #pragma unroll
        for (int rr = 0; rr < 4; ++rr)
            v[rr] = (unsigned short)f2bs(__expf(-fmaxf(acc[nt][rr], 0.f)));
        ((u16x4*)gdv)[((size_t)(p*1024 + bx*4 + g8))*256 + cg] = v;
    }
}

// ---------------------------------------------------------------- fused kernel
// 256 blocks x 512 thr (8 waves), waves_per_eu(2,2) => 256-VGPR budget.
// Lane owns TWO columns: c0 = wv*16+l15 (0..127), c1 = c0+128; batch row = g8.
// Weights truly register-resident: wf 96 VGPR + wih 72 VGPR = 168, pinned via asm.
__global__ __launch_bounds__(512)
__attribute__((amdgpu_waves_per_eu(2, 2)))
void k_fused(
    const float* __restrict__ x, const float* __restrict__ mask,
    const float* __restrict__ deltas, const float* __restrict__ meanset,
    const float* __restrict__ W_x, const float* __restrict__ b_x,
    const unsigned char* __restrict__ wihb8, const unsigned char* __restrict__ whh8,
    const unsigned short* __restrict__ gdv, const float* __restrict__ b_hh,
    const float* __restrict__ W_cls, const float* __restrict__ b_cls,
    float* __restrict__ ximp, float* __restrict__ numpart, float* __restrict__ denpart,
    float* __restrict__ yout, float* __restrict__ yscore)
{
    __shared__ unsigned char xl[16*200] __attribute__((aligned(16)));  // fp8 [x_h|m|1|0]
    __shared__ unsigned char hlds[2][4*272] __attribute__((aligned(16)));
    __shared__ float lossn[PT_][360], lossd[PT_][360];
    __shared__ float yred[4][8];

    int tid = threadIdx.x;
    int lane = tid & 63, wv = tid >> 6;        // wv 0..7
    int l15 = lane & 15, g8 = lane >> 4;
    int blk = blockIdx.x;
    int c0 = wv*16 + l15;                      // 0..127
    int c1 = c0 + 128;                         // 128..255

    // static pads of xl: col 178 = fp8(1.0)=0x38, 179..191 = 0
    for (int i = tid; i < 16*14; i += 512) {
        int r = i / 14, k = 178 + (i - r*14);
        xl[r*200 + k] = (k == 178) ? 0x38 : 0;
    }

    // owners: one per (row, v); 356 threads
    bool own = (tid < 4*V_);
    int r_o = tid / V_, v_o = tid - r_o*V_;
    int b_o = blk*4 + r_o;
    float wxd = 0.f, bx = 0.f, mnv = 0.f, last = 0.f;
    if (own) { wxd = W_x[v_o*V_ + v_o]; bx = b_x[v_o]; mnv = meanset[v_o]; }

    // ---- register-resident weights (both columns)
    long wih0[3][6], wih1[3][6], wf0[3][8], wf1[3][8];
    #pragma unroll
    for (int g = 0; g < 3; ++g) {
        #pragma unroll
        for (int kt = 0; kt < 6; ++kt) {
            wih0[g][kt] = *(const long*)(wihb8 + (size_t)(g*H_ + c0)*192 + kt*32 + g8*8);
            wih1[g][kt] = *(const long*)(wihb8 + (size_t)(g*H_ + c1)*192 + kt*32 + g8*8);
        }
        #pragma unroll
        for (int kt = 0; kt < 8; ++kt) {
            wf0[g][kt] = *(const long*)(whh8 + (size_t)(g*H_ + c0)*H_ + kt*32 + g8*8);
            wf1[g][kt] = *(const long*)(whh8 + (size_t)(g*H_ + c1)*H_ + kt*32 + g8*8);
        }
    }
    // pin: make values opaque so the scheduler cannot sink/remat the loads
    #pragma unroll
    for (int g = 0; g < 3; ++g) {
        #pragma unroll
        for (int kt = 0; kt < 6; ++kt) {
            asm volatile("" : "+v"(wih0[g][kt]));
            asm volatile("" : "+v"(wih1[g][kt]));
        }
        #pragma unroll
        for (int kt = 0; kt < 8; ++kt) {
            asm volatile("" : "+v"(wf0[g][kt]));
            asm volatile("" : "+v"(wf1[g][kt]));
        }
    }
    float bhh00 = b_hh[c0], bhh10 = b_hh[H_ + c0], bhh20 = b_hh[2*H_ + c0];
    float bhh01 = b_hh[c1], bhh11 = b_hh[H_ + c1], bhh21 = b_hh[2*H_ + c1];

    float h0 = 0.f, h1 = 0.f;

    for (int p = 0; p < NPH; ++p) {
        // ---- gamma prefetch (fragment-native, 8B/lane per column)
        u16x4 gdl0 = ((const u16x4*)gdv)[((size_t)(p*1024 + blk*4 + g8))*256 + c0];
        u16x4 gdl1 = ((const u16x4*)gdv)[((size_t)(p*1024 + blk*4 + g8))*256 + c1];

        // ================= stage: impute + ffill + loss + xl tile
        if (own) {
            const float* xb = x      + ((size_t)b_o*T_ + p*PT_)*V_ + v_o;
            const float* mb = mask   + ((size_t)b_o*T_ + p*PT_)*V_ + v_o;
            const float* db = deltas + ((size_t)b_o*T_ + p*PT_)*V_ + v_o;
            float xv[PT_], mv[PT_], dv[PT_];
            #pragma unroll
            for (int lt = 0; lt < PT_; ++lt) {
                xv[lt] = xb[lt*V_]; mv[lt] = mb[lt*V_]; dv[lt] = db[lt*V_];
            }
            #pragma unroll
            for (int lt = 0; lt < PT_; ++lt) {
                float xt = xv[lt], m = mv[lt], d = dv[lt];
                float gx = __expf(-fmaxf(fmaf(d, wxd, bx), 0.f));
                last = (m > 0.f) ? xt : last;
                float xu = gx*last + (1.f-gx)*mnv;
                float xh = m*xt + (1.f-m)*xu;
                ximp[((size_t)b_o*T_ + p*PT_ + lt)*V_ + v_o] = xh;
                int mr = r_o*4 + lt;
                int pk = __builtin_amdgcn_cvt_pk_fp8_f32(xh, m, 0, false);
                xl[mr*200 + v_o]      = (unsigned char)(pk & 0xFF);
                xl[mr*200 + V_ + v_o] = (unsigned char)((pk >> 8) & 0xFF);
                lossn[lt][tid] = fabsf(xt - xu)*m;
                lossd[lt][tid] = m;
            }
        }
        __syncthreads();

        // ---- loss reduce (wave 0)
        if (tid < 64) {
            int lt = tid >> 4, part = tid & 15;
            float n = 0.f, ds = 0.f;
            for (int j = part; j < 4*V_; j += 16) { n += lossn[lt][j]; ds += lossd[lt][j]; }
            n += __shfl_xor(n, 1); ds += __shfl_xor(ds, 1);
            n += __shfl_xor(n, 2); ds += __shfl_xor(ds, 2);
            n += __shfl_xor(n, 4); ds += __shfl_xor(ds, 4);
            n += __shfl_xor(n, 8); ds += __shfl_xor(ds, 8);
            if (part == 0) {
                int t = p*PT_ + lt;
                numpart[t*NB2 + blk] = n;
                denpart[t*NB2 + blk] = ds;
            }
        }

        // ================= gates GEMM: fp8, K=192, bias folded (init 0)
        f32x4 ar0 = {0.f,0.f,0.f,0.f}, az0 = ar0, an0 = ar0;
        f32x4 ar1 = ar0, az1 = ar0, an1 = ar0;
        #pragma unroll
        for (int kt = 0; kt < 6; ++kt) {
            long a = *(const long*)&xl[l15*200 + kt*32 + g8*8];
            ar0 = __builtin_amdgcn_mfma_f32_16x16x32_fp8_fp8(a, wih0[0][kt], ar0, 0,0,0);
            az0 = __builtin_amdgcn_mfma_f32_16x16x32_fp8_fp8(a, wih0[1][kt], az0, 0,0,0);
            an0 = __builtin_amdgcn_mfma_f32_16x16x32_fp8_fp8(a, wih0[2][kt], an0, 0,0,0);
            ar1 = __builtin_amdgcn_mfma_f32_16x16x32_fp8_fp8(a, wih1[0][kt], ar1, 0,0,0);
            az1 = __builtin_amdgcn_mfma_f32_16x16x32_fp8_fp8(a, wih1[1][kt], az1, 0,0,0);
            an1 = __builtin_amdgcn_mfma_f32_16x16x32_fp8_fp8(a, wih1[2][kt], an1, 0,0,0);
        }

        // ================= recurrence: 4 steps
        #pragma unroll
        for (int lt = 0; lt < PT_; ++lt) {
            const int cb = lt & 1;
            float hd0 = h0 * s2f(gdl0[lt]);
            float hd1 = h1 * s2f(gdl1[lt]);
            int pk = __builtin_amdgcn_cvt_pk_fp8_f32(hd0, hd1, 0, false);
            hlds[cb][g8*272 + c0] = (unsigned char)(pk & 0xFF);
            hlds[cb][g8*272 + c1] = (unsigned char)((pk >> 8) & 0xFF);
            __syncthreads();
            f32x4 s00 = {bhh00,bhh00,bhh00,bhh00};
            f32x4 s10 = {bhh10,bhh10,bhh10,bhh10};
            f32x4 s20 = {bhh20,bhh20,bhh20,bhh20};
            f32x4 s01 = {bhh01,bhh01,bhh01,bhh01};
            f32x4 s11 = {bhh11,bhh11,bhh11,bhh11};
            f32x4 s21 = {bhh21,bhh21,bhh21,bhh21};
            #pragma unroll
            for (int kt = 0; kt < 8; ++kt) {
                long a = *(const long*)&hlds[cb][(l15>>2)*272 + kt*32 + g8*8];
                s00 = __builtin_amdgcn_mfma_f32_16x16x32_fp8_fp8(a, wf0[0][kt], s00, 0,0,0);
                s10 = __builtin_amdgcn_mfma_f32_16x16x32_fp8_fp8(a, wf0[1][kt], s10, 0,0,0);
                s20 = __builtin_amdgcn_mfma_f32_16x16x32_fp8_fp8(a, wf0[2][kt], s20, 0,0,0);
                s01 = __builtin_amdgcn_mfma_f32_16x16x32_fp8_fp8(a, wf1[0][kt], s01, 0,0,0);
                s11 = __builtin_amdgcn_mfma_f32_16x16x32_fp8_fp8(a, wf1[1][kt], s11, 0,0,0);
                s21 = __builtin_amdgcn_mfma_f32_16x16x32_fp8_fp8(a, wf1[2][kt], s21, 0,0,0);
            }
            float rg0 = sig_(ar0[lt] + s00[0]);
            float zg0 = sig_(az0[lt] + s10[0]);
            float ng0 = tanh_(an0[lt] + rg0*s20[0]);
            h0 = (1.f - zg0)*ng0 + zg0*hd0;
            float rg1 = sig_(ar1[lt] + s01[0]);
            float zg1 = sig_(az1[lt] + s11[0]);
            float ng1 = tanh_(an1[lt] + rg1*s21[0]);
            h1 = (1.f - zg1)*ng1 + zg1*hd1;
        }
    }

    // ================= epilogue
    {
        float pr = h0 * W_cls[c0] + h1 * W_cls[c1];
        pr += __shfl_xor(pr, 1);
        pr += __shfl_xor(pr, 2);
        pr += __shfl_xor(pr, 4);
        pr += __shfl_xor(pr, 8);
        if (l15 == 0) yred[g8][wv] = pr;
        __syncthreads();
        if (tid < 4) {
            float s = b_cls[0];
            #pragma unroll
            for (int ww = 0; ww < 8; ++ww) s += yred[tid][ww];
            yout[blk*4 + tid]   = s;
            yscore[blk*4 + tid] = 1.f/(1.f+__expf(-s));
        }
    }
}

// ---------------------------------------------------------------- loss stage 1
__global__ __launch_bounds__(256) void k_loss_t(
    const float* __restrict__ numpart, const float* __restrict__ denpart,
    float* __restrict__ tpart)
{
    int t = blockIdx.x, tid = threadIdx.x;
    float n = numpart[t*NB2 + tid];
    float d = denpart[t*NB2 + tid];
    for (int off = 32; off; off >>= 1) { n += __shfl_down(n, off); d += __shfl_down(d, off); }
    __shared__ float sn[4], sd[4];
    int lane = tid & 63, wid = tid >> 6;
    if (lane == 0) { sn[wid] = n; sd[wid] = d; }
    __syncthreads();
    if (tid == 0) {
        float nn = sn[0]+sn[1]+sn[2]+sn[3], dd = sd[0]+sd[1]+sd[2]+sd[3];
        tpart[t] = nn / (dd + 1e-5f);
    }
}

// ---------------------------------------------------------------- loss stage 2
__global__ __launch_bounds__(128) void k_loss_final(
    const float* __restrict__ tpart, float* __restrict__ out_loss)
{
    int tid = threadIdx.x;
    float s = tpart[tid];
    for (int off = 32; off; off >>= 1) s += __shfl_down(s, off);
    __shared__ float sp[2];
    if ((tid&63)==0) sp[tid>>6] = s;
    __syncthreads();
    if (tid==0) out_loss[0] = sp[0] + sp[1];
}

static inline size_t al256(size_t x){ return (x + 255) & ~(size_t)255; }

extern "C" void kernel_launch(void* const* d_in, const int* in_sizes, int n_in,
                              void* d_out, int out_size, void* d_ws, size_t ws_size,
                              hipStream_t stream)
{
    const float* x      = (const float*)d_in[0];
    const float* mask   = (const float*)d_in[1];
    const float* deltas = (const float*)d_in[2];
    const float* meanset= (const float*)d_in[3];
    const float* W_h    = (const float*)d_in[4];
    const float* b_h    = (const float*)d_in[5];
    const float* W_x    = (const float*)d_in[6];
    const float* b_x    = (const float*)d_in[7];
    const float* W_ih   = (const float*)d_in[8];
    const float* b_ih   = (const float*)d_in[9];
    const float* W_hh   = (const float*)d_in[10];
    const float* b_hh   = (const float*)d_in[11];
    const float* W_cls  = (const float*)d_in[12];
    const float* b_cls  = (const float*)d_in[13];

    float* out    = (float*)d_out;
    float* ximp   = out;                        // B*T*V
    float* xloss  = out + (size_t)B_*T_*V_;     // 1
    float* yout   = xloss + 1;                  // B
    float* yscore = yout + B_;                  // B

    size_t off = 0;
    size_t off_whh8 = off; off = al256(off + (size_t)768*256);      // fp8
    size_t off_wih8 = off; off = al256(off + (size_t)768*192);      // fp8, bias folded
    size_t off_whp  = off; off = al256(off + (size_t)256*96*2);     // bf16, bias folded
    size_t off_gdv  = off; off = al256(off + (size_t)B_*T_*H_*2);   // gamma bf16 frag-native
    size_t off_np   = off; off = al256(off + (size_t)T_*NB2*4);
    size_t off_dp   = off; off = al256(off + (size_t)T_*NB2*4);
    size_t off_tp   = off; off = al256(off + (size_t)T_*4);
    if (off > ws_size) return;

    char* ws = (char*)d_ws;
    unsigned char* whh8 = (unsigned char*)(ws + off_whh8);
    unsigned char* wih8 = (unsigned char*)(ws + off_wih8);
    short* whp    = (short*)(ws + off_whp);
    unsigned short* gdv = (unsigned short*)(ws + off_gdv);
    float* numpart= (float*)(ws + off_np);
    float* denpart= (float*)(ws + off_dp);
    float* tpart  = (float*)(ws + off_tp);

    hipLaunchKernelGGL(k_cvt_fp8, dim3((768*256/4+255)/256), dim3(256), 0, stream, W_hh, whh8, 768*256);
    hipLaunchKernelGGL(k_prep_wih8, dim3((768*48+255)/256), dim3(256), 0, stream, W_ih, b_ih, wih8);
    hipLaunchKernelGGL(k_prep_whp, dim3((256*96+255)/256), dim3(256), 0, stream, W_h, b_h, whp);
    hipLaunchKernelGGL(k_gammah, dim3(256, 32), dim3(256), 0, stream, deltas, whp, gdv);
    hipLaunchKernelGGL(k_fused, dim3(NB2), dim3(512), 0, stream,
                       x, mask, deltas, meanset, W_x, b_x,
                       wih8, whh8, gdv, b_hh, W_cls, b_cls,
                       ximp, numpart, denpart, yout, yscore);
    hipLaunchKernelGGL(k_loss_t, dim3(T_), dim3(256), 0, stream, numpart, denpart, tpart);
    hipLaunchKernelGGL(k_loss_final, dim3(1), dim3(128), 0, stream, tpart, xloss);
}